// Round 17
// baseline (123.818 us; speedup 1.0000x reference)
//
#include <hip/hip_runtime.h>
#include <math.h>

#define N_ROWS 4096
#define DIM    256
#define P_SZ   5532
#define Q_SZ   5000
#define C_COLS 10532            // P+Q
#define TPAD   10624            // table rows padded to 83*128 (zero-filled)
#define PSTR   10624            // proj row stride in u16 elems == TPAD (full tiles)
#define NGR    (PSTR / 16)      // 1328 16B granules per proj row
#define K_SEL  701              // HARD_NUM + 1
#define SCALAR 30.0f
#define C2     (SCALAR * 1.4426950408889634f)   // log2(e)*30

typedef __attribute__((ext_vector_type(8))) short   short8;
typedef __attribute__((ext_vector_type(4))) float   float4_t;
typedef __attribute__((ext_vector_type(4))) unsigned short ushort4_t;
typedef __attribute__((ext_vector_type(8))) unsigned short ushort8_t;
typedef __attribute__((ext_vector_type(4))) unsigned int  uint4_t;

// ---------------- helpers ----------------
__device__ __forceinline__ unsigned short f2bf(float f) {   // fp32 -> bf16 RNE
    unsigned u = __float_as_uint(f);
    unsigned r = u + 0x7FFFu + ((u >> 16) & 1u);
    return (unsigned short)(r >> 16);
}
__device__ __forceinline__ float bf2f(unsigned short u) {
    return __uint_as_float((unsigned)u << 16);
}
__device__ __forceinline__ unsigned short key16(unsigned short u) { // order-preserving key
    return (u & 0x8000u) ? (unsigned short)(~u) : (unsigned short)(u | 0x8000u);
}
__device__ __forceinline__ float key2f16(unsigned key) {    // inverse: key -> float
    unsigned short b = (key & 0x8000u) ? (unsigned short)(key & 0x7FFFu)
                                       : (unsigned short)(~key & 0xFFFFu);
    return bf2f(b);
}
__device__ __forceinline__ void gload16(const void* g, void* l) {
    __builtin_amdgcn_global_load_lds(
        (const __attribute__((address_space(1))) unsigned int*)g,
        (__attribute__((address_space(3))) unsigned int*)l, 16, 0, 0);
}

// ---------------- fp32 -> bf16 pre-conversion (inputs + padded table) ----------------
#define NIN_G  (N_ROWS * DIM / 4)       // 262144 float4 granules
#define NTAB_G (TPAD * DIM / 4)         // 679936

__global__ __launch_bounds__(256) void convert_bf16(
    const float* __restrict__ inputs, const float* __restrict__ lut,
    const float* __restrict__ cq, unsigned short* __restrict__ in_bf,
    unsigned short* __restrict__ tab_bf)
{
    const int g = blockIdx.x * 256 + threadIdx.x;
    if (g >= NIN_G + NTAB_G) return;
    float4_t v;
    unsigned short* dst;
    if (g < NIN_G) {
        v = *(const float4_t*)&inputs[(size_t)g * 4];
        dst = in_bf + (size_t)g * 4;
    } else {
        const int t = g - NIN_G;
        const int row = t >> 6;                 // /(DIM/4)
        const int c4  = (t & 63) * 4;
        if (row < P_SZ)        v = *(const float4_t*)&lut[(size_t)row * DIM + c4];
        else if (row < C_COLS) v = *(const float4_t*)&cq[(size_t)(row - P_SZ) * DIM + c4];
        else                   v = (float4_t){0.f, 0.f, 0.f, 0.f};
        dst = tab_bf + (size_t)t * 4;
    }
    ushort4_t h = { f2bf(v.x), f2bf(v.y), f2bf(v.z), f2bf(v.w) };
    *(ushort4_t*)dst = h;
}

// ---------------- bf16 MFMA GEMM: proj(key16) = key16((in @ tab^T) * rel) ----------------
// Measured-best (R11/R16): BK=32 double-buffered global_load_lds with counted vmcnt,
// inside the 33792 B LDS union (A0,A1 @ 0/8K; B0,B1 @ 16K/24K; epilogue aliases all).
#define NWG_X 83
#define NWG_Y 32
#define NWG   (NWG_X * NWG_Y)   // 2656, divisible by 8
#define CSTR  132               // C-tile LDS row stride in elems (264 B, conflict-free)

__global__ __launch_bounds__(256) void gemm_proj(
    const unsigned short* __restrict__ in_bf,
    const unsigned short* __restrict__ tab_bf,
    const float* __restrict__ rel,
    unsigned short* __restrict__ proj)
{
    __shared__ __align__(16) unsigned short smem[128 * CSTR];   // 33792 B

    const int tid  = threadIdx.x;
    const int lane = tid & 63, wid = tid >> 6;
    const int wm = wid >> 1, wn = wid & 1;

    // XCD-bijective swizzle, col-major decode: each XCD chunk keeps full A in L2
    const int phys = blockIdx.x;
    const int wg   = (phys & 7) * (NWG / 8) + (phys >> 3);
    const int bx   = wg >> 5;               // 0..82 col-block
    const int by   = wg & 31;               // 0..31 row-block
    const int row0 = by * 128, col0 = bx * 128;

    float4_t acc[4][4];
    #pragma unroll
    for (int i = 0; i < 4; ++i)
        #pragma unroll
        for (int j = 0; j < 4; ++j)
            acc[i][j] = (float4_t){0.f, 0.f, 0.f, 0.f};

    // stage one BK=32 tile pair into buffer b: elem (r,k) at byte r*64 + ((k*2)^((r&3)<<4));
    // linear LDS dest, inverse-swizzled global source (rule #21)
    auto STAGE = [&](int b, int k0) {
        #pragma unroll
        for (int it = 0; it < 2; ++it) {
            const int g  = it * 256 + tid;       // 0..511
            const int r  = g >> 2;               // 0..127
            const int kb = ((g & 3) * 16) ^ ((r & 3) << 4);   // src byte within 64B row
            gload16(in_bf  + (size_t)(row0 + r) * DIM + k0 + (kb >> 1),
                    (char*)smem + b * 8192 + g * 16);
            gload16(tab_bf + (size_t)(col0 + r) * DIM + k0 + (kb >> 1),
                    (char*)smem + 16384 + b * 8192 + g * 16);
        }
    };

    STAGE(0, 0);                                  // 4 loads in flight
    #pragma unroll
    for (int t = 0; t < 8; ++t) {
        if (t < 7) {
            STAGE((t + 1) & 1, (t + 1) * 32);     // 8 in flight
            asm volatile("s_waitcnt vmcnt(4)" ::: "memory");   // own current-tile 4 done
        } else {
            asm volatile("s_waitcnt vmcnt(0)" ::: "memory");
        }
        __builtin_amdgcn_s_barrier();             // all waves' current tile staged

        const char* At = (const char*)smem + (t & 1) * 8192;
        const char* Bt = (const char*)smem + 16384 + (t & 1) * 8192;
        const int krow = lane & 15;
        const int kb   = (lane >> 4) << 4;        // 16B k-slot within 64B row
        short8 af[4], bfr[4];
        #pragma unroll
        for (int i = 0; i < 4; ++i) {
            const int r = wm * 64 + i * 16 + krow;
            af[i] = *(const short8*)(At + r * 64 + (kb ^ ((r & 3) << 4)));
        }
        #pragma unroll
        for (int j = 0; j < 4; ++j) {
            const int r = wn * 64 + j * 16 + krow;
            bfr[j] = *(const short8*)(Bt + r * 64 + (kb ^ ((r & 3) << 4)));
        }
        #pragma unroll
        for (int i = 0; i < 4; ++i)
            #pragma unroll
            for (int j = 0; j < 4; ++j)
                acc[i][j] = __builtin_amdgcn_mfma_f32_16x16x32_bf16(af[i], bfr[j], acc[i][j], 0, 0, 0);
        __builtin_amdgcn_s_barrier();             // reads done before next stage overwrites
    }

    // epilogue: C layout col=lane&15, row=(lane>>4)*4+rr  [m89]
    // stage key16(bf16 C) in LDS (row stride CSTR), then coalesced 16B stores
    const int lr = (lane >> 4) << 2;
    const int lc = lane & 15;
    #pragma unroll
    for (int j = 0; j < 4; ++j) {
        const int cl  = wn * 64 + j * 16 + lc;        // tile-local col
        const int col = col0 + cl;
        const bool pad = (col >= C_COLS);
        const float rl = pad ? 0.f : rel[col];
        #pragma unroll
        for (int i = 0; i < 4; ++i) {
            const int rbase = wm * 64 + i * 16 + lr;  // tile-local row
            #pragma unroll
            for (int rr = 0; rr < 4; ++rr)
                smem[(rbase + rr) * CSTR + cl] =
                    pad ? (unsigned short)0u : key16(f2bf(acc[i][j][rr] * rl));
        }
    }
    __syncthreads();
    #pragma unroll
    for (int it = 0; it < 8; ++it) {
        const int g = it * 256 + tid;
        const int r = g >> 4;
        const int c8 = (g & 15) * 8;                  // col in elems
        *(ushort8_t*)(proj + (size_t)(row0 + r) * PSTR + col0 + c8) =
            *(const ushort8_t*)&smem[r * CSTR + c8];
    }
}

// ---------------- per-row: LDS-resident ballot select + stash masked LSE ---------------
// proj holds key16 (monotone). Row staged ONCE into LDS via global_load_lds (linear
// dest) — all subsequent sweeps read LDS, so codegen cannot turn them into global
// re-reads (R15 failure mode) and there are no per-element atomics (R4/R6 failure
// mode). 6-pass ballot binary search restricted to [128,192) (701st-largest is
// positive since each row has ~5266 positive entries; v <= 1 < 2.0 — validated
// absmax 0.0 in R13). Stash keys >= b1<<8 in own-lane slots, h2 + scan + masked exp.
// Mean fused via scaled atomicAdd into pre-zeroed out (validated R12/R13).
#define SCAP  32
__global__ __launch_bounds__(256) void row_loss_kernel(
    const unsigned short* __restrict__ proj, const int* __restrict__ labels,
    float* __restrict__ out)
{
    __shared__ __align__(16) unsigned short vals[PSTR];   // 21248 B
    __shared__ unsigned short stash[SCAP * 256];          // 16384 B, lane-major
    __shared__ unsigned h2[256];                          // 1024 B
    __shared__ unsigned wsum[2][4];
    __shared__ float    fsum[4];
    __shared__ unsigned sel_sub, ovf;

    const int tid = threadIdx.x, lane = tid & 63, wid = tid >> 6;
    const int row = blockIdx.x;
    const unsigned short* prow = proj + (size_t)row * PSTR;
    const bool tailv = (1280 + tid < NGR);            // tid < 48

    h2[tid] = 0;
    if (tid == 0) ovf = 0;

    // ---- stage row into LDS (linear dest: granule g at byte g*16) ----
    #pragma unroll
    for (int it = 0; it < 5; ++it) {
        const int g = it * 256 + tid;
        gload16(prow + (size_t)g * 8, (char*)vals + (size_t)g * 16);
    }
    if (tailv)
        gload16(prow + (size_t)(1280 + tid) * 8, (char*)vals + (size_t)(1280 + tid) * 16);
    __syncthreads();    // drains vmcnt (global_load_lds) + lgkmcnt before any read

    const int gt = tailv ? (1280 + tid) : 0;          // clamped tail granule (masked)
    auto LD = [&](int g) -> uint4_t {
        return *(const uint4_t*)((const char*)vals + g * 16);
    };

    // ---- 6-pass ballot binary search on key top byte in [128,192) ----
    unsigned lo = 128, hi = 192, cnt_hi = 0;
    for (int pass = 0; pass < 6; ++pass) {
        const unsigned mid = (lo + hi) >> 1;
        const unsigned hiT = mid << 24;
        unsigned c = 0;                               // wave-uniform (SALU accumulation)
        #pragma unroll
        for (int it = 0; it < 5; ++it) {
            const uint4_t w = LD(it * 256 + tid);
            #pragma unroll
            for (int d = 0; d < 4; ++d) {
                c += (unsigned)__popcll(__ballot(w[d] >= hiT));          // hi u16 elem
                c += (unsigned)__popcll(__ballot((w[d] << 16) >= hiT));  // lo u16 elem
            }
        }
        {
            const uint4_t w = LD(gt);
            #pragma unroll
            for (int d = 0; d < 4; ++d) {
                c += (unsigned)__popcll(__ballot(tailv && (w[d] >= hiT)));
                c += (unsigned)__popcll(__ballot(tailv && ((w[d] << 16) >= hiT)));
            }
        }
        if (lane == 0) wsum[pass & 1][wid] = c;
        __syncthreads();
        const unsigned total = wsum[pass & 1][0] + wsum[pass & 1][1]
                             + wsum[pass & 1][2] + wsum[pass & 1][3];
        if (total >= K_SEL) lo = mid;                 // uniform update
        else { hi = mid; cnt_hi = total; }
    }
    const unsigned b1 = lo;                           // boundary byte-bin
    const unsigned k2 = K_SEL - cnt_hi;               // residual rank within bin
    const unsigned kfloor = b1 << 8;
    const unsigned kceil  = kfloor + 256u;

    // ---- stash candidate keys (>= kfloor) into own-lane LDS slots ----
    unsigned cnt = 0;
    auto ST = [&](unsigned key) {
        if (key >= kfloor) {
            if (cnt < SCAP) stash[cnt * 256 + tid] = (unsigned short)key;
            else ovf = 1u;
            ++cnt;
        }
    };
    #pragma unroll
    for (int it = 0; it < 5; ++it) {
        const uint4_t w = LD(it * 256 + tid);
        #pragma unroll
        for (int d = 0; d < 4; ++d) { ST(w[d] & 0xFFFFu); ST(w[d] >> 16); }
    }
    if (tailv) {
        const uint4_t w = LD(gt);
        #pragma unroll
        for (int d = 0; d < 4; ++d) { ST(w[d] & 0xFFFFu); ST(w[d] >> 16); }
    }
    __syncthreads();

    float s = 0.f;
    unsigned bkey;
    if (ovf == 0) {
        // ---- h2 sub-hist from stash (bin b1 only; sub-bin = low byte) ----
        for (unsigned c = 0; c < cnt; ++c) {
            const unsigned key = stash[c * 256 + tid];
            if (key < kceil) atomicAdd(&h2[key & 0xFFu], 1u);
        }
        __syncthreads();
        // ---- scan: 256 sub-bins -> exact boundary key ----
        {
            const unsigned c = h2[tid];
            unsigned incl = c;
            #pragma unroll
            for (int off = 1; off < 64; off <<= 1) {
                const unsigned t = __shfl_down(incl, off, 64);
                if (lane + off < 64) incl += t;
            }
            if (lane == 0) wsum[0][wid] = incl;
            __syncthreads();
            unsigned above = incl - c;
            for (int w = wid + 1; w < 4; ++w) above += wsum[0][w];
            if (above < k2 && above + c >= k2) sel_sub = (unsigned)tid;
        }
        __syncthreads();
        bkey = kfloor | sel_sub;
        // ---- exp sum over stash (deterministic per-thread order) ----
        for (unsigned c = 0; c < cnt; ++c) {
            const unsigned key = stash[c * 256 + tid];
            if (key >= bkey) s += exp2f(C2 * key2f16(key) - C2);
        }
    } else {
        // ---- fallback (exact, rare): LDS re-sweeps ----
        auto SB = [&](unsigned w) {
            const unsigned lv = w & 0xFFFFu, hv = w >> 16;
            if ((lv >> 8) == b1) atomicAdd(&h2[lv & 0xFFu], 1u);
            if ((hv >> 8) == b1) atomicAdd(&h2[hv & 0xFFu], 1u);
        };
        #pragma unroll
        for (int it = 0; it < 5; ++it) {
            const uint4_t w = LD(it * 256 + tid);
            #pragma unroll
            for (int d = 0; d < 4; ++d) SB(w[d]);
        }
        if (tailv) {
            const uint4_t w = LD(gt);
            #pragma unroll
            for (int d = 0; d < 4; ++d) SB(w[d]);
        }
        __syncthreads();
        {
            const unsigned c = h2[tid];
            unsigned incl = c;
            #pragma unroll
            for (int off = 1; off < 64; off <<= 1) {
                const unsigned t = __shfl_down(incl, off, 64);
                if (lane + off < 64) incl += t;
            }
            if (lane == 0) wsum[0][wid] = incl;
            __syncthreads();
            unsigned above = incl - c;
            for (int w = wid + 1; w < 4; ++w) above += wsum[0][w];
            if (above < k2 && above + c >= k2) sel_sub = (unsigned)tid;
        }
        __syncthreads();
        bkey = kfloor | sel_sub;
        auto EX = [&](unsigned w) {
            const unsigned lv = w & 0xFFFFu, hv = w >> 16;
            if (lv >= bkey) s += exp2f(C2 * key2f16(lv) - C2);
            if (hv >= bkey) s += exp2f(C2 * key2f16(hv) - C2);
        };
        #pragma unroll
        for (int it = 0; it < 5; ++it) {
            const uint4_t w = LD(it * 256 + tid);
            #pragma unroll
            for (int d = 0; d < 4; ++d) EX(w[d]);
        }
        if (tailv) {
            const uint4_t w = LD(gt);
            #pragma unroll
            for (int d = 0; d < 4; ++d) EX(w[d]);
        }
    }

    // ---- block reduce + fused mean ----
    #pragma unroll
    for (int off = 1; off < 64; off <<= 1) {
        const float t = __shfl_down(s, off, 64);
        if (lane + off < 64) s += t;
    }
    if (lane == 0) fsum[wid] = s;
    __syncthreads();

    if (tid == 0) {
        float total = fsum[0] + fsum[1] + fsum[2] + fsum[3];
        const unsigned ulk = vals[labels[row]];       // label < P_SZ, key16 domain
        const float pl = key2f16(ulk);
        if (ulk < bkey) total += exp2f(C2 * pl - C2);
        const float loss = SCALAR * 1.0f + logf(total) - SCALAR * pl;
        atomicAdd(out, loss * (1.0f / (float)N_ROWS));
    }
}

extern "C" void kernel_launch(void* const* d_in, const int* in_sizes, int n_in,
                              void* d_out, int out_size, void* d_ws, size_t ws_size,
                              hipStream_t stream) {
    const float* inputs = (const float*)d_in[0];
    const int*   labels = (const int*)d_in[1];
    const float* lut    = (const float*)d_in[2];
    const float* cq     = (const float*)d_in[3];
    const float* rel    = (const float*)d_in[4];
    float* out = (float*)d_out;

    // ws: in_bf [4096*256] | tab_bf [10624*256] | proj [4096*10624] u16
    unsigned short* in_bf  = (unsigned short*)d_ws;
    unsigned short* tab_bf = in_bf  + (size_t)N_ROWS * DIM;
    unsigned short* proj   = tab_bf + (size_t)TPAD * DIM;

    hipMemsetAsync(out, 0, sizeof(float), stream);
    convert_bf16<<<(NIN_G + NTAB_G) / 256, 256, 0, stream>>>(inputs, lut, cq, in_bf, tab_bf);
    gemm_proj<<<NWG, 256, 0, stream>>>(in_bf, tab_bf, rel, proj);
    row_loss_kernel<<<N_ROWS, 256, 0, stream>>>(proj, labels, out);
}

// Round 18
// 95.901 us; speedup vs baseline: 1.2911x; 1.2911x over previous
//
#include <hip/hip_runtime.h>
#include <math.h>

#define N_ROWS 4096
#define DIM    256
#define P_SZ   5532
#define Q_SZ   5000
#define C_COLS 10532            // P+Q
#define TPAD   10624            // table rows padded to 83*128 (zero-filled)
#define PSTR   10624            // proj row stride in u16 elems == TPAD (full tiles)
#define NGR    (PSTR / 16)      // 1328 uint4 granules per proj row (16B = 8 elems)
#define K_SEL  701              // HARD_NUM + 1
#define SCALAR 30.0f
#define C2     (SCALAR * 1.4426950408889634f)   // log2(e)*30

typedef __attribute__((ext_vector_type(8))) short   short8;
typedef __attribute__((ext_vector_type(4))) float   float4_t;
typedef __attribute__((ext_vector_type(4))) unsigned short ushort4_t;
typedef __attribute__((ext_vector_type(8))) unsigned short ushort8_t;
typedef __attribute__((ext_vector_type(4))) unsigned int  uint4_t;

// ---------------- helpers ----------------
__device__ __forceinline__ unsigned short f2bf(float f) {   // fp32 -> bf16 RNE
    unsigned u = __float_as_uint(f);
    unsigned r = u + 0x7FFFu + ((u >> 16) & 1u);
    return (unsigned short)(r >> 16);
}
__device__ __forceinline__ float bf2f(unsigned short u) {
    return __uint_as_float((unsigned)u << 16);
}
__device__ __forceinline__ unsigned short key16(unsigned short u) { // order-preserving key
    return (u & 0x8000u) ? (unsigned short)(~u) : (unsigned short)(u | 0x8000u);
}
__device__ __forceinline__ float key2f16(unsigned key) {    // inverse: key -> float
    unsigned short b = (key & 0x8000u) ? (unsigned short)(key & 0x7FFFu)
                                       : (unsigned short)(~key & 0xFFFFu);
    return bf2f(b);
}
__device__ __forceinline__ void gload16(const void* g, void* l) {
    __builtin_amdgcn_global_load_lds(
        (const __attribute__((address_space(1))) unsigned int*)g,
        (__attribute__((address_space(3))) unsigned int*)l, 16, 0, 0);
}

// ---------------- fp32 -> bf16 pre-conversion (inputs + padded table) ----------------
#define NIN_G  (N_ROWS * DIM / 4)       // 262144 float4 granules
#define NTAB_G (TPAD * DIM / 4)         // 679936

__global__ __launch_bounds__(256) void convert_bf16(
    const float* __restrict__ inputs, const float* __restrict__ lut,
    const float* __restrict__ cq, unsigned short* __restrict__ in_bf,
    unsigned short* __restrict__ tab_bf)
{
    const int g = blockIdx.x * 256 + threadIdx.x;
    if (g >= NIN_G + NTAB_G) return;
    float4_t v;
    unsigned short* dst;
    if (g < NIN_G) {
        v = *(const float4_t*)&inputs[(size_t)g * 4];
        dst = in_bf + (size_t)g * 4;
    } else {
        const int t = g - NIN_G;
        const int row = t >> 6;                 // /(DIM/4)
        const int c4  = (t & 63) * 4;
        if (row < P_SZ)        v = *(const float4_t*)&lut[(size_t)row * DIM + c4];
        else if (row < C_COLS) v = *(const float4_t*)&cq[(size_t)(row - P_SZ) * DIM + c4];
        else                   v = (float4_t){0.f, 0.f, 0.f, 0.f};
        dst = tab_bf + (size_t)t * 4;
    }
    ushort4_t h = { f2bf(v.x), f2bf(v.y), f2bf(v.z), f2bf(v.w) };
    *(ushort4_t*)dst = h;
}

// ---------------- bf16 MFMA GEMM: proj(key16) = key16((in @ tab^T) * rel) ----------------
// BK=32 double-buffered global_load_lds with counted vmcnt, INSIDE the 33792 B
// LDS union (A0,A1 @ 0/8K; B0,B1 @ 16K/24K; epilogue C-tile aliases all).
#define NWG_X 83
#define NWG_Y 32
#define NWG   (NWG_X * NWG_Y)   // 2656, divisible by 8
#define CSTR  132               // C-tile LDS row stride in elems (264 B, conflict-free)

__global__ __launch_bounds__(256) void gemm_proj(
    const unsigned short* __restrict__ in_bf,
    const unsigned short* __restrict__ tab_bf,
    const float* __restrict__ rel,
    unsigned short* __restrict__ proj)
{
    __shared__ __align__(16) unsigned short smem[128 * CSTR];   // 33792 B

    const int tid  = threadIdx.x;
    const int lane = tid & 63, wid = tid >> 6;
    const int wm = wid >> 1, wn = wid & 1;

    // XCD-bijective swizzle, col-major decode: each XCD chunk keeps full A in L2
    const int phys = blockIdx.x;
    const int wg   = (phys & 7) * (NWG / 8) + (phys >> 3);
    const int bx   = wg >> 5;               // 0..82 col-block
    const int by   = wg & 31;               // 0..31 row-block
    const int row0 = by * 128, col0 = bx * 128;

    float4_t acc[4][4];
    #pragma unroll
    for (int i = 0; i < 4; ++i)
        #pragma unroll
        for (int j = 0; j < 4; ++j)
            acc[i][j] = (float4_t){0.f, 0.f, 0.f, 0.f};

    // stage one BK=32 tile pair into buffer b: elem (r,k) at byte r*64 + ((k*2)^((r&3)<<4));
    // linear LDS dest, inverse-swizzled global source (rule #21)
    auto STAGE = [&](int b, int k0) {
        #pragma unroll
        for (int it = 0; it < 2; ++it) {
            const int g  = it * 256 + tid;       // 0..511
            const int r  = g >> 2;               // 0..127
            const int kb = ((g & 3) * 16) ^ ((r & 3) << 4);   // src byte within 64B row
            gload16(in_bf  + (size_t)(row0 + r) * DIM + k0 + (kb >> 1),
                    (char*)smem + b * 8192 + g * 16);
            gload16(tab_bf + (size_t)(col0 + r) * DIM + k0 + (kb >> 1),
                    (char*)smem + 16384 + b * 8192 + g * 16);
        }
    };

    STAGE(0, 0);                                  // 4 loads in flight
    #pragma unroll
    for (int t = 0; t < 8; ++t) {
        if (t < 7) {
            STAGE((t + 1) & 1, (t + 1) * 32);     // 8 in flight
            asm volatile("s_waitcnt vmcnt(4)" ::: "memory");   // own current-tile 4 done
        } else {
            asm volatile("s_waitcnt vmcnt(0)" ::: "memory");
        }
        __builtin_amdgcn_s_barrier();             // all waves' current tile staged

        const char* At = (const char*)smem + (t & 1) * 8192;
        const char* Bt = (const char*)smem + 16384 + (t & 1) * 8192;
        const int krow = lane & 15;
        const int kb   = (lane >> 4) << 4;        // 16B k-slot within 64B row
        short8 af[4], bfr[4];
        #pragma unroll
        for (int i = 0; i < 4; ++i) {
            const int r = wm * 64 + i * 16 + krow;
            af[i] = *(const short8*)(At + r * 64 + (kb ^ ((r & 3) << 4)));
        }
        #pragma unroll
        for (int j = 0; j < 4; ++j) {
            const int r = wn * 64 + j * 16 + krow;
            bfr[j] = *(const short8*)(Bt + r * 64 + (kb ^ ((r & 3) << 4)));
        }
        #pragma unroll
        for (int i = 0; i < 4; ++i)
            #pragma unroll
            for (int j = 0; j < 4; ++j)
                acc[i][j] = __builtin_amdgcn_mfma_f32_16x16x32_bf16(af[i], bfr[j], acc[i][j], 0, 0, 0);
        __builtin_amdgcn_s_barrier();             // reads done before next stage overwrites
    }

    // epilogue: C layout col=lane&15, row=(lane>>4)*4+rr  [m89]
    // stage key16(bf16 C) in LDS (row stride CSTR), then coalesced 16B stores
    const int lr = (lane >> 4) << 2;
    const int lc = lane & 15;
    #pragma unroll
    for (int j = 0; j < 4; ++j) {
        const int cl  = wn * 64 + j * 16 + lc;        // tile-local col
        const int col = col0 + cl;
        const bool pad = (col >= C_COLS);
        const float rl = pad ? 0.f : rel[col];
        #pragma unroll
        for (int i = 0; i < 4; ++i) {
            const int rbase = wm * 64 + i * 16 + lr;  // tile-local row
            #pragma unroll
            for (int rr = 0; rr < 4; ++rr)
                smem[(rbase + rr) * CSTR + cl] =
                    pad ? (unsigned short)0u : key16(f2bf(acc[i][j][rr] * rl));
        }
    }
    __syncthreads();
    #pragma unroll
    for (int it = 0; it < 8; ++it) {
        const int g = it * 256 + tid;
        const int r = g >> 4;
        const int c8 = (g & 15) * 8;                  // col in elems
        *(ushort8_t*)(proj + (size_t)(row0 + r) * PSTR + col0 + c8) =
            *(const ushort8_t*)&smem[r * CSTR + c8];
    }
}

// ---------------- per-row: ballot binary-search select + stash masked LSE --------------
// proj holds key16 (monotone). 8 ballot-count passes on the key top byte (v_cmp is
// the only VALU op; popcount+accumulate ride the scalar pipe). Sub-byte: stash keys
// >= b1<<8 into own-lane LDS slots, 256-bin h2 + scan + masked exp over the stash.
// Exact register-resweep fallback on overflow. (Measured-best configuration, R11.)
#define SCAP  32
__global__ __launch_bounds__(256) void row_loss_kernel(
    const unsigned short* __restrict__ proj, const int* __restrict__ labels,
    float* __restrict__ row_loss)
{
    __shared__ unsigned short stash[SCAP * 256]; // 16384 B, lane-major (own-thread only)
    __shared__ unsigned h2[256];                 // 1024 B
    __shared__ unsigned wsum[2][4];
    __shared__ float    fsum[4];
    __shared__ unsigned sel_sub, ovf;

    const int tid = threadIdx.x, lane = tid & 63, wid = tid >> 6;
    const int row = blockIdx.x;
    const uint4_t* prow = (const uint4_t*)(proj + (size_t)row * PSTR);

    h2[tid] = 0;
    if (tid == 0) ovf = 0;
    // (visibility guaranteed by the search-pass barriers below)

    // ---- single global sweep: row into registers (packed u16 pairs)
    const bool tailv = (1280 + tid < NGR);            // tid < 48
    uint4_t r0 = prow[tid];
    uint4_t r1 = prow[256 + tid];
    uint4_t r2 = prow[512 + tid];
    uint4_t r3 = prow[768 + tid];
    uint4_t r4 = prow[1024 + tid];
    uint4_t r5 = prow[tailv ? 1280 + tid : 1279];     // clamped (guarded below)

    // ---- binary search on key top byte: b1 = max b with count(key >= b<<8) >= K_SEL
    unsigned lo = 0, hi = 256, cnt_hi = 0;
    for (int pass = 0; pass < 8; ++pass) {
        const unsigned mid = (lo + hi) >> 1;
        const unsigned hiT = mid << 24;
        unsigned c = 0;                               // wave-uniform (SALU accumulation)
        auto CB = [&](unsigned w) {
            c += (unsigned)__popcll(__ballot(w >= hiT));          // hi u16 elem
            c += (unsigned)__popcll(__ballot((w << 16) >= hiT));  // lo u16 elem
        };
        #pragma unroll
        for (int d = 0; d < 4; ++d) CB(r0[d]);
        #pragma unroll
        for (int d = 0; d < 4; ++d) CB(r1[d]);
        #pragma unroll
        for (int d = 0; d < 4; ++d) CB(r2[d]);
        #pragma unroll
        for (int d = 0; d < 4; ++d) CB(r3[d]);
        #pragma unroll
        for (int d = 0; d < 4; ++d) CB(r4[d]);
        #pragma unroll
        for (int d = 0; d < 4; ++d) {
            c += (unsigned)__popcll(__ballot(tailv && (r5[d] >= hiT)));
            c += (unsigned)__popcll(__ballot(tailv && ((r5[d] << 16) >= hiT)));
        }
        if (lane == 0) wsum[pass & 1][wid] = c;
        __syncthreads();
        const unsigned total = wsum[pass & 1][0] + wsum[pass & 1][1]
                             + wsum[pass & 1][2] + wsum[pass & 1][3];
        if (total >= K_SEL) lo = mid;                 // uniform update
        else { hi = mid; cnt_hi = total; }
    }
    const unsigned b1 = lo;                           // boundary byte-bin
    const unsigned k2 = K_SEL - cnt_hi;               // residual rank within bin
    const unsigned kfloor = b1 << 8;
    const unsigned kceil  = kfloor + 256u;

    // ---- stash candidate keys (>= kfloor) into own-lane LDS slots
    unsigned cnt = 0;
    auto ST = [&](unsigned key) {
        if (key >= kfloor) {
            if (cnt < SCAP) stash[cnt * 256 + tid] = (unsigned short)key;
            else ovf = 1u;
            ++cnt;
        }
    };
    auto SW = [&](uint4_t w) {
        #pragma unroll
        for (int d = 0; d < 4; ++d) { ST(w[d] & 0xFFFFu); ST(w[d] >> 16); }
    };
    SW(r0); SW(r1); SW(r2); SW(r3); SW(r4);
    if (tailv) SW(r5);
    __syncthreads();

    float s = 0.f;
    unsigned bkey;
    if (ovf == 0) {
        // ---- h2 sub-hist from stash (bin b1 only; sub-bin = low byte)
        for (unsigned c = 0; c < cnt; ++c) {
            const unsigned key = stash[c * 256 + tid];
            if (key < kceil) atomicAdd(&h2[key & 0xFFu], 1u);
        }
        __syncthreads();
        // ---- scan 2: 256 sub-bins -> exact boundary key
        {
            const unsigned c = h2[tid];
            unsigned incl = c;
            #pragma unroll
            for (int off = 1; off < 64; off <<= 1) {
                const unsigned t = __shfl_down(incl, off, 64);
                if (lane + off < 64) incl += t;
            }
            if (lane == 0) wsum[0][wid] = incl;
            __syncthreads();
            unsigned above = incl - c;
            for (int w = wid + 1; w < 4; ++w) above += wsum[0][w];
            if (above < k2 && above + c >= k2) sel_sub = (unsigned)tid;
        }
        __syncthreads();
        bkey = kfloor | sel_sub;
        // ---- exp sum over stash (deterministic per-thread order)
        for (unsigned c = 0; c < cnt; ++c) {
            const unsigned key = stash[c * 256 + tid];
            if (key >= bkey) s += exp2f(C2 * key2f16(key) - C2);
        }
    } else {
        // ---- fallback (exact, rare): register re-sweeps
        auto SB = [&](unsigned w) {
            const unsigned lv = w & 0xFFFFu, hv = w >> 16;
            if ((lv >> 8) == b1) atomicAdd(&h2[lv & 0xFFu], 1u);
            if ((hv >> 8) == b1) atomicAdd(&h2[hv & 0xFFu], 1u);
        };
        #pragma unroll
        for (int d = 0; d < 4; ++d) SB(r0[d]);
        #pragma unroll
        for (int d = 0; d < 4; ++d) SB(r1[d]);
        #pragma unroll
        for (int d = 0; d < 4; ++d) SB(r2[d]);
        #pragma unroll
        for (int d = 0; d < 4; ++d) SB(r3[d]);
        #pragma unroll
        for (int d = 0; d < 4; ++d) SB(r4[d]);
        if (tailv) {
            #pragma unroll
            for (int d = 0; d < 4; ++d) SB(r5[d]);
        }
        __syncthreads();
        {
            const unsigned c = h2[tid];
            unsigned incl = c;
            #pragma unroll
            for (int off = 1; off < 64; off <<= 1) {
                const unsigned t = __shfl_down(incl, off, 64);
                if (lane + off < 64) incl += t;
            }
            if (lane == 0) wsum[0][wid] = incl;
            __syncthreads();
            unsigned above = incl - c;
            for (int w = wid + 1; w < 4; ++w) above += wsum[0][w];
            if (above < k2 && above + c >= k2) sel_sub = (unsigned)tid;
        }
        __syncthreads();
        bkey = kfloor | sel_sub;
        auto EX = [&](unsigned w) {
            const unsigned lv = w & 0xFFFFu, hv = w >> 16;
            if (lv >= bkey) s += exp2f(C2 * key2f16(lv) - C2);
            if (hv >= bkey) s += exp2f(C2 * key2f16(hv) - C2);
        };
        #pragma unroll
        for (int d = 0; d < 4; ++d) EX(r0[d]);
        #pragma unroll
        for (int d = 0; d < 4; ++d) EX(r1[d]);
        #pragma unroll
        for (int d = 0; d < 4; ++d) EX(r2[d]);
        #pragma unroll
        for (int d = 0; d < 4; ++d) EX(r3[d]);
        #pragma unroll
        for (int d = 0; d < 4; ++d) EX(r4[d]);
        if (tailv) {
            #pragma unroll
            for (int d = 0; d < 4; ++d) EX(r5[d]);
        }
    }

    // ---- block reduce + finish
    #pragma unroll
    for (int off = 1; off < 64; off <<= 1) {
        const float t = __shfl_down(s, off, 64);
        if (lane + off < 64) s += t;
    }
    if (lane == 0) fsum[wid] = s;
    __syncthreads();

    if (tid == 0) {
        float total = fsum[0] + fsum[1] + fsum[2] + fsum[3];
        const unsigned ulk = ((const unsigned short*)prow)[labels[row]];  // label < P_SZ
        const float pl = key2f16(ulk);
        if (ulk < bkey) total += exp2f(C2 * pl - C2);
        row_loss[row] = SCALAR * 1.0f + logf(total) - SCALAR * pl;
    }
}

// ---------------- final mean ----------------
__global__ __launch_bounds__(256) void final_reduce(
    const float* __restrict__ row_loss, float* __restrict__ out)
{
    __shared__ float fred[4];
    const int tid = threadIdx.x, lane = tid & 63, wid = tid >> 6;
    float s = 0.f;
    for (int i = tid; i < N_ROWS; i += 256) s += row_loss[i];
    #pragma unroll
    for (int off = 1; off < 64; off <<= 1) {
        const float t = __shfl_down(s, off, 64);
        if (lane + off < 64) s += t;
    }
    if (lane == 0) fred[wid] = s;
    __syncthreads();
    if (tid == 0) out[0] = (fred[0] + fred[1] + fred[2] + fred[3]) / (float)N_ROWS;
}

extern "C" void kernel_launch(void* const* d_in, const int* in_sizes, int n_in,
                              void* d_out, int out_size, void* d_ws, size_t ws_size,
                              hipStream_t stream) {
    const float* inputs = (const float*)d_in[0];
    const int*   labels = (const int*)d_in[1];
    const float* lut    = (const float*)d_in[2];
    const float* cq     = (const float*)d_in[3];
    const float* rel    = (const float*)d_in[4];
    float* out = (float*)d_out;

    // ws: in_bf [4096*256] | tab_bf [10624*256] | proj [4096*10624] u16 | row_loss
    unsigned short* in_bf  = (unsigned short*)d_ws;
    unsigned short* tab_bf = in_bf  + (size_t)N_ROWS * DIM;
    unsigned short* proj   = tab_bf + (size_t)TPAD * DIM;
    float* rl_buf = (float*)(proj + (size_t)N_ROWS * PSTR);

    convert_bf16<<<(NIN_G + NTAB_G) / 256, 256, 0, stream>>>(inputs, lut, cq, in_bf, tab_bf);
    gemm_proj<<<NWG, 256, 0, stream>>>(in_bf, tab_bf, rel, proj);
    row_loss_kernel<<<N_ROWS, 256, 0, stream>>>(proj, labels, rl_buf);
    final_reduce<<<1, 256, 0, stream>>>(rl_buf, out);
}